// Round 1
// baseline (490.553 us; speedup 1.0000x reference)
//
#include <hip/hip_runtime.h>
#include <hip/hip_bf16.h>

#define TOKENS 8192
#define DM 512
#define NE 8
#define HID 1024
#define NSLOT (TOKENS * 2)

typedef __bf16 bf16x8 __attribute__((ext_vector_type(8)));
typedef float floatx4 __attribute__((ext_vector_type(4)));
typedef unsigned short u16x8 __attribute__((ext_vector_type(8)));

__device__ __forceinline__ unsigned short f2bf(float f) {
    union { float f; unsigned u; } c; c.f = f;
    unsigned u = c.u;
    u += 0x7fffu + ((u >> 16) & 1u);   // RNE
    return (unsigned short)(u >> 16);
}

// ---------------- init: zero y and the tiny counters ----------------
__global__ void init_kernel(float* __restrict__ y, int* counts, int* cursor) {
    const size_t n4 = (size_t)TOKENS * DM / 4;
    float4* y4 = (float4*)y;
    for (size_t i = (size_t)blockIdx.x * blockDim.x + threadIdx.x; i < n4;
         i += (size_t)gridDim.x * blockDim.x)
        y4[i] = make_float4(0.f, 0.f, 0.f, 0.f);
    if (blockIdx.x == 0 && threadIdx.x < NE) {
        counts[threadIdx.x] = 0;
        cursor[threadIdx.x] = 0;
    }
}

// ---------------- x fp32 -> bf16 (row-major K kept) ----------------
__global__ void cvt_x_kernel(const float* __restrict__ src, unsigned short* __restrict__ dst) {
    int i = blockIdx.x * blockDim.x + threadIdx.x;        // one thread per 8 elems
    const float4* s = (const float4*)src + (size_t)i * 2;
    float4 a = s[0], b = s[1];
    u16x8 r;
    r[0] = f2bf(a.x); r[1] = f2bf(a.y); r[2] = f2bf(a.z); r[3] = f2bf(a.w);
    r[4] = f2bf(b.x); r[5] = f2bf(b.y); r[6] = f2bf(b.z); r[7] = f2bf(b.w);
    *((u16x8*)dst + i) = r;
}

// ------- W [E][K][N] fp32 -> Wt [E][N][K] bf16 (32x32 LDS tile transpose) -------
__global__ void cvt_transpose_kernel(const float* __restrict__ src, unsigned short* __restrict__ dst,
                                     int K, int N) {
    __shared__ float tile[32][33];
    const int tk = K >> 5, tn = N >> 5;
    int b = blockIdx.x;
    int e = b / (tk * tn);
    int rem = b % (tk * tn);
    int kt = rem / tn, nt = rem % tn;
    int tx = threadIdx.x & 31, ty = threadIdx.x >> 5;     // ty in [0,8)
    const float* s = src + ((size_t)e * K + kt * 32) * N + nt * 32;
    #pragma unroll
    for (int i = 0; i < 32; i += 8)
        tile[ty + i][tx] = s[(size_t)(ty + i) * N + tx];
    __syncthreads();
    unsigned short* d = dst + ((size_t)e * N + nt * 32) * K + kt * 32;
    #pragma unroll
    for (int i = 0; i < 32; i += 8)
        d[(size_t)(ty + i) * K + tx] = f2bf(tile[tx][ty + i]);
}

// ---------------- router: fp32 logits, top-2, softmax over 2 ----------------
// one wave per token; lane l owns d = l + 64*j
__global__ void router_kernel(const float* __restrict__ x, const float* __restrict__ Wg,
                              const float* __restrict__ bg,
                              int* __restrict__ top_idx, float* __restrict__ top_p,
                              int* counts) {
    int lane = threadIdx.x & 63, wave = threadIdx.x >> 6;
    int t = blockIdx.x * 4 + wave;
    float acc[NE];
    #pragma unroll
    for (int e = 0; e < NE; e++) acc[e] = 0.f;
    const float* xr = x + (size_t)t * DM;
    #pragma unroll
    for (int j = 0; j < 8; j++) {
        int d = lane + j * 64;
        float xv = xr[d];
        const float4* wr = (const float4*)(Wg + (size_t)d * NE);
        float4 w0 = wr[0], w1 = wr[1];
        acc[0] += xv * w0.x; acc[1] += xv * w0.y; acc[2] += xv * w0.z; acc[3] += xv * w0.w;
        acc[4] += xv * w1.x; acc[5] += xv * w1.y; acc[6] += xv * w1.z; acc[7] += xv * w1.w;
    }
    #pragma unroll
    for (int e = 0; e < NE; e++) {
        float v = acc[e];
        #pragma unroll
        for (int off = 32; off > 0; off >>= 1) v += __shfl_down(v, off, 64);
        acc[e] = v;
    }
    if (lane == 0) {
        float best = -1e30f, second = -1e30f;
        int bi = 0, si = 0;
        #pragma unroll
        for (int e = 0; e < NE; e++) {
            float v = acc[e] + bg[e];
            if (v > best) { second = best; si = bi; best = v; bi = e; }
            else if (v > second) { second = v; si = e; }
        }
        float ex = __expf(second - best);
        float inv = 1.f / (1.f + ex);
        top_idx[t * 2] = bi;  top_idx[t * 2 + 1] = si;
        top_p[t * 2] = inv;   top_p[t * 2 + 1] = ex * inv;
        atomicAdd(&counts[bi], 1);
        atomicAdd(&counts[si], 1);
    }
}

// ---------------- prefix over 8 counts ----------------
__global__ void prefix_kernel(const int* __restrict__ counts, int* __restrict__ offsets) {
    if (threadIdx.x == 0 && blockIdx.x == 0) {
        int s = 0;
        for (int e = 0; e < NE; e++) { offsets[e] = s; s += counts[e]; }
    }
}

// ---------------- build compact expert buckets ----------------
__global__ void build_kernel(const int* __restrict__ top_idx, const float* __restrict__ top_p,
                             const int* __restrict__ offsets, int* cursor,
                             int* __restrict__ rows, float* __restrict__ gates,
                             int* __restrict__ slot_of) {
    int t = blockIdx.x * blockDim.x + threadIdx.x;
    if (t >= TOKENS) return;
    #pragma unroll
    for (int k = 0; k < 2; k++) {
        int e = top_idx[t * 2 + k];
        int i = atomicAdd(&cursor[e], 1);
        int slot = offsets[e] + i;
        rows[slot] = t;
        gates[slot] = top_p[t * 2 + k];
        slot_of[t * 2 + k] = slot;
    }
}

// ---------------- GEMM1: H = silu(X*W1) .* (X*W3), bf16 out ----------------
// tile 64x64, BK=64, 4 waves (each a 32x32 quadrant), mfma 16x16x32 bf16
__global__ __launch_bounds__(256) void gemm1_kernel(
    const unsigned short* __restrict__ xb,     // [TOKENS][DM]
    const unsigned short* __restrict__ w1t,    // [E][HID][DM]
    const unsigned short* __restrict__ w3t,    // [E][HID][DM]
    unsigned short* __restrict__ Hb,           // [NSLOT][HID]
    const int* __restrict__ rows, const int* __restrict__ counts,
    const int* __restrict__ offsets) {
    const int e = blockIdx.z, mt = blockIdx.y, nt = blockIdx.x;
    const int cnt = counts[e];
    if (mt * 64 >= cnt) return;
    const int off = offsets[e];

    __shared__ unsigned short As[64 * 72];
    __shared__ unsigned short B1s[64 * 72];
    __shared__ unsigned short B3s[64 * 72];

    const int tid = threadIdx.x;
    const int srow = tid >> 2;               // 0..63
    const int schunk = (tid & 3) * 16;       // 16 bf16 = 32B per thread-chunk
    const int ar = mt * 64 + srow;
    const int tok = rows[off + (ar < cnt ? ar : 0)];
    const unsigned short* ap = xb + (size_t)tok * DM + schunk;
    const unsigned short* b1p = w1t + ((size_t)e * HID + nt * 64 + srow) * DM + schunk;
    const unsigned short* b3p = w3t + ((size_t)e * HID + nt * 64 + srow) * DM + schunk;
    unsigned short* asw = As + srow * 72 + schunk;
    unsigned short* b1w = B1s + srow * 72 + schunk;
    unsigned short* b3w = B3s + srow * 72 + schunk;

    const int lane = tid & 63, wave = tid >> 6;
    const int m0 = (wave >> 1) * 32, n0 = (wave & 1) * 32;
    const int l15 = lane & 15, quad = lane >> 4;

    floatx4 acc1[2][2], acc3[2][2];
    #pragma unroll
    for (int i = 0; i < 2; i++)
        #pragma unroll
        for (int j = 0; j < 2; j++) {
            acc1[i][j] = (floatx4){0.f, 0.f, 0.f, 0.f};
            acc3[i][j] = (floatx4){0.f, 0.f, 0.f, 0.f};
        }

    for (int k0 = 0; k0 < DM; k0 += 64) {
        uint4 a0 = *(const uint4*)(ap + k0);
        uint4 a1 = *(const uint4*)(ap + k0 + 8);
        uint4 c0 = *(const uint4*)(b1p + k0);
        uint4 c1 = *(const uint4*)(b1p + k0 + 8);
        uint4 d0 = *(const uint4*)(b3p + k0);
        uint4 d1 = *(const uint4*)(b3p + k0 + 8);
        __syncthreads();
        *(uint4*)asw = a0; *(uint4*)(asw + 8) = a1;
        *(uint4*)b1w = c0; *(uint4*)(b1w + 8) = c1;
        *(uint4*)b3w = d0; *(uint4*)(b3w + 8) = d1;
        __syncthreads();
        #pragma unroll
        for (int kk = 0; kk < 2; kk++) {
            bf16x8 af[2], bf1[2], bf3[2];
            #pragma unroll
            for (int mi = 0; mi < 2; mi++)
                af[mi] = *(const bf16x8*)(As + (m0 + mi * 16 + l15) * 72 + kk * 32 + quad * 8);
            #pragma unroll
            for (int ni = 0; ni < 2; ni++) {
                bf1[ni] = *(const bf16x8*)(B1s + (n0 + ni * 16 + l15) * 72 + kk * 32 + quad * 8);
                bf3[ni] = *(const bf16x8*)(B3s + (n0 + ni * 16 + l15) * 72 + kk * 32 + quad * 8);
            }
            #pragma unroll
            for (int mi = 0; mi < 2; mi++)
                #pragma unroll
                for (int ni = 0; ni < 2; ni++) {
                    acc1[mi][ni] = __builtin_amdgcn_mfma_f32_16x16x32_bf16(af[mi], bf1[ni], acc1[mi][ni], 0, 0, 0);
                    acc3[mi][ni] = __builtin_amdgcn_mfma_f32_16x16x32_bf16(af[mi], bf3[ni], acc3[mi][ni], 0, 0, 0);
                }
        }
    }
    // epilogue: silu(a1)*a3 -> bf16; C/D layout: col=lane&15, row=quad*4+reg
    #pragma unroll
    for (int mi = 0; mi < 2; mi++) {
        #pragma unroll
        for (int r = 0; r < 4; r++) {
            int mloc = m0 + mi * 16 + quad * 4 + r;
            int gi = mt * 64 + mloc;
            if (gi < cnt) {
                size_t rowbase = (size_t)(off + gi) * HID + nt * 64 + n0;
                #pragma unroll
                for (int ni = 0; ni < 2; ni++) {
                    float z1 = acc1[mi][ni][r];
                    float z3 = acc3[mi][ni][r];
                    float h = (z1 / (1.f + __expf(-z1))) * z3;
                    Hb[rowbase + ni * 16 + l15] = f2bf(h);
                }
            }
        }
    }
}

// ---------------- GEMM2: P = H * W2 (per compact slot), fp32 out ----------------
__global__ __launch_bounds__(256) void gemm2_kernel(
    const unsigned short* __restrict__ Hb,    // [NSLOT][HID]
    const unsigned short* __restrict__ w2t,   // [E][DM][HID]
    float* __restrict__ P,                    // [NSLOT][DM] or null
    float* __restrict__ y,                    // atomic fallback
    const int* __restrict__ rows, const float* __restrict__ gates,
    const int* __restrict__ counts, const int* __restrict__ offsets) {
    const int e = blockIdx.z, mt = blockIdx.y, nt = blockIdx.x;
    const int cnt = counts[e];
    if (mt * 64 >= cnt) return;
    const int off = offsets[e];

    __shared__ unsigned short As[64 * 72];
    __shared__ unsigned short Bs[64 * 72];

    const int tid = threadIdx.x;
    const int srow = tid >> 2;
    const int schunk = (tid & 3) * 16;
    const int ar = mt * 64 + srow;
    const int aslot = off + (ar < cnt ? ar : 0);
    const unsigned short* ap = Hb + (size_t)aslot * HID + schunk;
    const unsigned short* bp = w2t + ((size_t)e * DM + nt * 64 + srow) * HID + schunk;
    unsigned short* asw = As + srow * 72 + schunk;
    unsigned short* bsw = Bs + srow * 72 + schunk;

    const int lane = tid & 63, wave = tid >> 6;
    const int m0 = (wave >> 1) * 32, n0 = (wave & 1) * 32;
    const int l15 = lane & 15, quad = lane >> 4;

    floatx4 acc[2][2];
    #pragma unroll
    for (int i = 0; i < 2; i++)
        #pragma unroll
        for (int j = 0; j < 2; j++) acc[i][j] = (floatx4){0.f, 0.f, 0.f, 0.f};

    for (int k0 = 0; k0 < HID; k0 += 64) {
        uint4 a0 = *(const uint4*)(ap + k0);
        uint4 a1 = *(const uint4*)(ap + k0 + 8);
        uint4 b0 = *(const uint4*)(bp + k0);
        uint4 b1 = *(const uint4*)(bp + k0 + 8);
        __syncthreads();
        *(uint4*)asw = a0; *(uint4*)(asw + 8) = a1;
        *(uint4*)bsw = b0; *(uint4*)(bsw + 8) = b1;
        __syncthreads();
        #pragma unroll
        for (int kk = 0; kk < 2; kk++) {
            bf16x8 af[2], bf[2];
            #pragma unroll
            for (int mi = 0; mi < 2; mi++)
                af[mi] = *(const bf16x8*)(As + (m0 + mi * 16 + l15) * 72 + kk * 32 + quad * 8);
            #pragma unroll
            for (int ni = 0; ni < 2; ni++)
                bf[ni] = *(const bf16x8*)(Bs + (n0 + ni * 16 + l15) * 72 + kk * 32 + quad * 8);
            #pragma unroll
            for (int mi = 0; mi < 2; mi++)
                #pragma unroll
                for (int ni = 0; ni < 2; ni++)
                    acc[mi][ni] = __builtin_amdgcn_mfma_f32_16x16x32_bf16(af[mi], bf[ni], acc[mi][ni], 0, 0, 0);
        }
    }
    const bool direct = (P == nullptr);
    #pragma unroll
    for (int mi = 0; mi < 2; mi++) {
        #pragma unroll
        for (int r = 0; r < 4; r++) {
            int mloc = m0 + mi * 16 + quad * 4 + r;
            int gi = mt * 64 + mloc;
            if (gi < cnt) {
                int slot = off + gi;
                #pragma unroll
                for (int ni = 0; ni < 2; ni++) {
                    int col = nt * 64 + n0 + ni * 16 + l15;
                    float v = acc[mi][ni][r];
                    if (direct) {
                        int tokr = rows[slot];
                        atomicAdd(&y[(size_t)tokr * DM + col], gates[slot] * v);
                    } else {
                        P[(size_t)slot * DM + col] = v;
                    }
                }
            }
        }
    }
}

// ---------------- combine: y[t] = g0*P[s0] + g1*P[s1] ----------------
__global__ void combine_kernel(const float* __restrict__ P, const int* __restrict__ slot_of,
                               const float* __restrict__ top_p, float* __restrict__ y) {
    int i = blockIdx.x * blockDim.x + threadIdx.x;    // per float4
    int t = i / (DM / 4);
    int c4 = i % (DM / 4);
    int s0 = slot_of[t * 2], s1 = slot_of[t * 2 + 1];
    float g0 = top_p[t * 2], g1 = top_p[t * 2 + 1];
    float4 a = ((const float4*)P)[(size_t)s0 * (DM / 4) + c4];
    float4 b = ((const float4*)P)[(size_t)s1 * (DM / 4) + c4];
    float4 o;
    o.x = g0 * a.x + g1 * b.x;
    o.y = g0 * a.y + g1 * b.y;
    o.z = g0 * a.z + g1 * b.z;
    o.w = g0 * a.w + g1 * b.w;
    ((float4*)y)[i] = o;
}

extern "C" void kernel_launch(void* const* d_in, const int* in_sizes, int n_in,
                              void* d_out, int out_size, void* d_ws, size_t ws_size,
                              hipStream_t stream) {
    (void)in_sizes; (void)n_in; (void)out_size;
    const float* x  = (const float*)d_in[0];
    const float* Wg = (const float*)d_in[1];
    const float* bg = (const float*)d_in[2];
    const float* W1 = (const float*)d_in[3];
    const float* W3 = (const float*)d_in[4];
    const float* W2 = (const float*)d_in[5];
    float* y = (float*)d_out;

    char* p = (char*)d_ws;
    auto carve = [&](size_t bytes) -> char* {
        char* r = p;
        p += (bytes + 255) & ~(size_t)255;
        return r;
    };
    unsigned short* xb   = (unsigned short*)carve((size_t)TOKENS * DM * 2);
    unsigned short* w1t  = (unsigned short*)carve((size_t)NE * DM * HID * 2);
    unsigned short* w3t  = (unsigned short*)carve((size_t)NE * DM * HID * 2);
    unsigned short* w2t  = (unsigned short*)carve((size_t)NE * HID * DM * 2);
    unsigned short* Hb   = (unsigned short*)carve((size_t)NSLOT * HID * 2);
    int*   rows    = (int*)carve(NSLOT * 4);
    float* gates   = (float*)carve(NSLOT * 4);
    int*   slot_of = (int*)carve(NSLOT * 4);
    int*   tidx    = (int*)carve((size_t)TOKENS * 2 * 4);
    float* tp      = (float*)carve((size_t)TOKENS * 2 * 4);
    int*   counts  = (int*)carve(256);
    int*   cursor  = (int*)carve(256);
    int*   offsets = (int*)carve(256);
    size_t base_need = (size_t)(p - (char*)d_ws);
    const size_t PBYTES = (size_t)NSLOT * DM * 4;
    float* P = nullptr;
    if (ws_size >= base_need + PBYTES) P = (float*)carve(PBYTES);

    init_kernel<<<dim3(1024), dim3(256), 0, stream>>>(y, counts, cursor);
    cvt_x_kernel<<<dim3((TOKENS * DM / 8) / 256), dim3(256), 0, stream>>>(x, xb);
    cvt_transpose_kernel<<<dim3(NE * (DM / 32) * (HID / 32)), dim3(256), 0, stream>>>(W1, w1t, DM, HID);
    cvt_transpose_kernel<<<dim3(NE * (DM / 32) * (HID / 32)), dim3(256), 0, stream>>>(W3, w3t, DM, HID);
    cvt_transpose_kernel<<<dim3(NE * (HID / 32) * (DM / 32)), dim3(256), 0, stream>>>(W2, w2t, HID, DM);
    router_kernel<<<dim3(TOKENS / 4), dim3(256), 0, stream>>>(x, Wg, bg, tidx, tp, counts);
    prefix_kernel<<<dim3(1), dim3(64), 0, stream>>>(counts, offsets);
    build_kernel<<<dim3(TOKENS / 256), dim3(256), 0, stream>>>(tidx, tp, offsets, cursor, rows, gates, slot_of);
    gemm1_kernel<<<dim3(HID / 64, 128, NE), dim3(256), 0, stream>>>(xb, w1t, w3t, Hb, rows, counts, offsets);
    gemm2_kernel<<<dim3(DM / 64, 128, NE), dim3(256), 0, stream>>>(Hb, w2t, P, y, rows, gates, counts, offsets);
    if (P != nullptr)
        combine_kernel<<<dim3((TOKENS * DM / 4) / 256), dim3(256), 0, stream>>>(P, slot_of, tp, y);
}

// Round 2
// 248.162 us; speedup vs baseline: 1.9767x; 1.9767x over previous
//
#include <hip/hip_runtime.h>
#include <hip/hip_bf16.h>

#define TOKENS 8192
#define DM 512
#define NE 8
#define HID 1024
#define NSLOT (TOKENS * 2)
#define NB 32          // token blocks for hist/build (256 tokens each)

typedef __bf16 bf16x8 __attribute__((ext_vector_type(8)));
typedef float floatx4 __attribute__((ext_vector_type(4)));
typedef unsigned short u16x8 __attribute__((ext_vector_type(8)));

__device__ __forceinline__ unsigned short f2bf(float f) {
    union { float f; unsigned u; } c; c.f = f;
    unsigned u = c.u;
    u += 0x7fffu + ((u >> 16) & 1u);   // RNE
    return (unsigned short)(u >> 16);
}

// ---------------- init: zero y ----------------
__global__ void init_kernel(float* __restrict__ y) {
    const size_t n4 = (size_t)TOKENS * DM / 4;
    float4* y4 = (float4*)y;
    for (size_t i = (size_t)blockIdx.x * blockDim.x + threadIdx.x; i < n4;
         i += (size_t)gridDim.x * blockDim.x)
        y4[i] = make_float4(0.f, 0.f, 0.f, 0.f);
}

// ---------------- x fp32 -> bf16 (row-major K kept) ----------------
__global__ void cvt_x_kernel(const float* __restrict__ src, unsigned short* __restrict__ dst) {
    int i = blockIdx.x * blockDim.x + threadIdx.x;        // one thread per 8 elems
    const float4* s = (const float4*)src + (size_t)i * 2;
    float4 a = s[0], b = s[1];
    u16x8 r;
    r[0] = f2bf(a.x); r[1] = f2bf(a.y); r[2] = f2bf(a.z); r[3] = f2bf(a.w);
    r[4] = f2bf(b.x); r[5] = f2bf(b.y); r[6] = f2bf(b.z); r[7] = f2bf(b.w);
    *((u16x8*)dst + i) = r;
}

// ------- W [E][K][N] fp32 -> Wt [E][N][K] bf16 (32x32 LDS tile transpose) -------
__global__ void cvt_transpose_kernel(const float* __restrict__ src, unsigned short* __restrict__ dst,
                                     int K, int N) {
    __shared__ float tile[32][33];
    const int tk = K >> 5, tn = N >> 5;
    int b = blockIdx.x;
    int e = b / (tk * tn);
    int rem = b % (tk * tn);
    int kt = rem / tn, nt = rem % tn;
    int tx = threadIdx.x & 31, ty = threadIdx.x >> 5;     // ty in [0,8)
    const float* s = src + ((size_t)e * K + kt * 32) * N + nt * 32;
    #pragma unroll
    for (int i = 0; i < 32; i += 8)
        tile[ty + i][tx] = s[(size_t)(ty + i) * N + tx];
    __syncthreads();
    unsigned short* d = dst + ((size_t)e * N + nt * 32) * K + kt * 32;
    #pragma unroll
    for (int i = 0; i < 32; i += 8)
        d[(size_t)(ty + i) * K + tx] = f2bf(tile[tx][ty + i]);
}

// ---------------- router: fp32 logits, top-2, softmax over 2 ----------------
// one wave per token; lane l owns d = l + 64*j. NO atomics.
__global__ void router_kernel(const float* __restrict__ x, const float* __restrict__ Wg,
                              const float* __restrict__ bg,
                              int* __restrict__ top_idx, float* __restrict__ top_p) {
    int lane = threadIdx.x & 63, wave = threadIdx.x >> 6;
    int t = blockIdx.x * 4 + wave;
    float acc[NE];
    #pragma unroll
    for (int e = 0; e < NE; e++) acc[e] = 0.f;
    const float* xr = x + (size_t)t * DM;
    #pragma unroll
    for (int j = 0; j < 8; j++) {
        int d = lane + j * 64;
        float xv = xr[d];
        const float4* wr = (const float4*)(Wg + (size_t)d * NE);
        float4 w0 = wr[0], w1 = wr[1];
        acc[0] += xv * w0.x; acc[1] += xv * w0.y; acc[2] += xv * w0.z; acc[3] += xv * w0.w;
        acc[4] += xv * w1.x; acc[5] += xv * w1.y; acc[6] += xv * w1.z; acc[7] += xv * w1.w;
    }
    #pragma unroll
    for (int e = 0; e < NE; e++) {
        float v = acc[e];
        #pragma unroll
        for (int off = 32; off > 0; off >>= 1) v += __shfl_down(v, off, 64);
        acc[e] = v;
    }
    if (lane == 0) {
        float best = -1e30f, second = -1e30f;
        int bi = 0, si = 0;
        #pragma unroll
        for (int e = 0; e < NE; e++) {
            float v = acc[e] + bg[e];
            if (v > best) { second = best; si = bi; best = v; bi = e; }
            else if (v > second) { second = v; si = e; }
        }
        float ex = __expf(second - best);
        float inv = 1.f / (1.f + ex);
        top_idx[t * 2] = bi;  top_idx[t * 2 + 1] = si;
        top_p[t * 2] = inv;   top_p[t * 2 + 1] = ex * inv;
    }
}

// ---------------- per-block LDS histogram (no global atomics) ----------------
__global__ void hist_kernel(const int* __restrict__ top_idx, int* __restrict__ block_hist) {
    __shared__ int h[NE];
    int b = blockIdx.x, tid = threadIdx.x;
    if (tid < NE) h[tid] = 0;
    __syncthreads();
    int t = b * 256 + tid;
    atomicAdd(&h[top_idx[t * 2]], 1);
    atomicAdd(&h[top_idx[t * 2 + 1]], 1);
    __syncthreads();
    if (tid < NE) block_hist[b * NE + tid] = h[tid];
}

// ---------------- scan: counts, offsets, per-block bases ----------------
__global__ void prefix_kernel(const int* __restrict__ block_hist, int* __restrict__ counts,
                              int* __restrict__ offsets, int* __restrict__ bases) {
    int e = threadIdx.x;
    if (e < NE) {
        int run = 0;
        for (int b = 0; b < NB; b++) { bases[b * NE + e] = run; run += block_hist[b * NE + e]; }
        counts[e] = run;
    }
    __syncthreads();
    if (e == 0) {
        int s = 0;
        for (int ee = 0; ee < NE; ee++) { offsets[ee] = s; s += counts[ee]; }
    }
    __syncthreads();
    if (e < NE) {
        int off = offsets[e];
        for (int b = 0; b < NB; b++) bases[b * NE + e] += off;
    }
}

// ---------------- build compact expert buckets (LDS cursors only) ----------------
__global__ void build_kernel(const int* __restrict__ top_idx, const float* __restrict__ top_p,
                             const int* __restrict__ bases,
                             int* __restrict__ rows, float* __restrict__ gates,
                             int* __restrict__ slot_of) {
    __shared__ int cur[NE];
    int b = blockIdx.x, tid = threadIdx.x;
    if (tid < NE) cur[tid] = bases[b * NE + tid];
    __syncthreads();
    int t = b * 256 + tid;
    #pragma unroll
    for (int k = 0; k < 2; k++) {
        int e = top_idx[t * 2 + k];
        int slot = atomicAdd(&cur[e], 1);
        rows[slot] = t;
        gates[slot] = top_p[t * 2 + k];
        slot_of[t * 2 + k] = slot;
    }
}

// ---------------- GEMM1: H = silu(X*W1) .* (X*W3), bf16 out ----------------
// tile 64x64, BK=64, 4 waves (each a 32x32 quadrant), mfma 16x16x32 bf16
__global__ __launch_bounds__(256) void gemm1_kernel(
    const unsigned short* __restrict__ xb,     // [TOKENS][DM]
    const unsigned short* __restrict__ w1t,    // [E][HID][DM]
    const unsigned short* __restrict__ w3t,    // [E][HID][DM]
    unsigned short* __restrict__ Hb,           // [NSLOT][HID]
    const int* __restrict__ rows, const int* __restrict__ counts,
    const int* __restrict__ offsets) {
    const int e = blockIdx.z, mt = blockIdx.y, nt = blockIdx.x;
    const int cnt = counts[e];
    if (mt * 64 >= cnt) return;
    const int off = offsets[e];

    __shared__ unsigned short As[64 * 72];
    __shared__ unsigned short B1s[64 * 72];
    __shared__ unsigned short B3s[64 * 72];

    const int tid = threadIdx.x;
    const int srow = tid >> 2;               // 0..63
    const int schunk = (tid & 3) * 16;       // 16 bf16 = 32B per thread-chunk
    const int ar = mt * 64 + srow;
    const int tok = rows[off + (ar < cnt ? ar : 0)];
    const unsigned short* ap = xb + (size_t)tok * DM + schunk;
    const unsigned short* b1p = w1t + ((size_t)e * HID + nt * 64 + srow) * DM + schunk;
    const unsigned short* b3p = w3t + ((size_t)e * HID + nt * 64 + srow) * DM + schunk;
    unsigned short* asw = As + srow * 72 + schunk;
    unsigned short* b1w = B1s + srow * 72 + schunk;
    unsigned short* b3w = B3s + srow * 72 + schunk;

    const int lane = tid & 63, wave = tid >> 6;
    const int m0 = (wave >> 1) * 32, n0 = (wave & 1) * 32;
    const int l15 = lane & 15, quad = lane >> 4;

    floatx4 acc1[2][2], acc3[2][2];
    #pragma unroll
    for (int i = 0; i < 2; i++)
        #pragma unroll
        for (int j = 0; j < 2; j++) {
            acc1[i][j] = (floatx4){0.f, 0.f, 0.f, 0.f};
            acc3[i][j] = (floatx4){0.f, 0.f, 0.f, 0.f};
        }

    for (int k0 = 0; k0 < DM; k0 += 64) {
        uint4 a0 = *(const uint4*)(ap + k0);
        uint4 a1 = *(const uint4*)(ap + k0 + 8);
        uint4 c0 = *(const uint4*)(b1p + k0);
        uint4 c1 = *(const uint4*)(b1p + k0 + 8);
        uint4 d0 = *(const uint4*)(b3p + k0);
        uint4 d1 = *(const uint4*)(b3p + k0 + 8);
        __syncthreads();
        *(uint4*)asw = a0; *(uint4*)(asw + 8) = a1;
        *(uint4*)b1w = c0; *(uint4*)(b1w + 8) = c1;
        *(uint4*)b3w = d0; *(uint4*)(b3w + 8) = d1;
        __syncthreads();
        #pragma unroll
        for (int kk = 0; kk < 2; kk++) {
            bf16x8 af[2], bf1[2], bf3[2];
            #pragma unroll
            for (int mi = 0; mi < 2; mi++)
                af[mi] = *(const bf16x8*)(As + (m0 + mi * 16 + l15) * 72 + kk * 32 + quad * 8);
            #pragma unroll
            for (int ni = 0; ni < 2; ni++) {
                bf1[ni] = *(const bf16x8*)(B1s + (n0 + ni * 16 + l15) * 72 + kk * 32 + quad * 8);
                bf3[ni] = *(const bf16x8*)(B3s + (n0 + ni * 16 + l15) * 72 + kk * 32 + quad * 8);
            }
            #pragma unroll
            for (int mi = 0; mi < 2; mi++)
                #pragma unroll
                for (int ni = 0; ni < 2; ni++) {
                    acc1[mi][ni] = __builtin_amdgcn_mfma_f32_16x16x32_bf16(af[mi], bf1[ni], acc1[mi][ni], 0, 0, 0);
                    acc3[mi][ni] = __builtin_amdgcn_mfma_f32_16x16x32_bf16(af[mi], bf3[ni], acc3[mi][ni], 0, 0, 0);
                }
        }
    }
    // epilogue: silu(a1)*a3 -> bf16; C/D layout: col=lane&15, row=quad*4+reg
    #pragma unroll
    for (int mi = 0; mi < 2; mi++) {
        #pragma unroll
        for (int r = 0; r < 4; r++) {
            int mloc = m0 + mi * 16 + quad * 4 + r;
            int gi = mt * 64 + mloc;
            if (gi < cnt) {
                size_t rowbase = (size_t)(off + gi) * HID + nt * 64 + n0;
                #pragma unroll
                for (int ni = 0; ni < 2; ni++) {
                    float z1 = acc1[mi][ni][r];
                    float z3 = acc3[mi][ni][r];
                    float h = (z1 / (1.f + __expf(-z1))) * z3;
                    Hb[rowbase + ni * 16 + l15] = f2bf(h);
                }
            }
        }
    }
}

// ---------------- GEMM2: P = H * W2 (per compact slot), fp32 out ----------------
__global__ __launch_bounds__(256) void gemm2_kernel(
    const unsigned short* __restrict__ Hb,    // [NSLOT][HID]
    const unsigned short* __restrict__ w2t,   // [E][DM][HID]
    float* __restrict__ P,                    // [NSLOT][DM] or null
    float* __restrict__ y,                    // atomic fallback
    const int* __restrict__ rows, const float* __restrict__ gates,
    const int* __restrict__ counts, const int* __restrict__ offsets) {
    const int e = blockIdx.z, mt = blockIdx.y, nt = blockIdx.x;
    const int cnt = counts[e];
    if (mt * 64 >= cnt) return;
    const int off = offsets[e];

    __shared__ unsigned short As[64 * 72];
    __shared__ unsigned short Bs[64 * 72];

    const int tid = threadIdx.x;
    const int srow = tid >> 2;
    const int schunk = (tid & 3) * 16;
    const int ar = mt * 64 + srow;
    const int aslot = off + (ar < cnt ? ar : 0);
    const unsigned short* ap = Hb + (size_t)aslot * HID + schunk;
    const unsigned short* bp = w2t + ((size_t)e * DM + nt * 64 + srow) * HID + schunk;
    unsigned short* asw = As + srow * 72 + schunk;
    unsigned short* bsw = Bs + srow * 72 + schunk;

    const int lane = tid & 63, wave = tid >> 6;
    const int m0 = (wave >> 1) * 32, n0 = (wave & 1) * 32;
    const int l15 = lane & 15, quad = lane >> 4;

    floatx4 acc[2][2];
    #pragma unroll
    for (int i = 0; i < 2; i++)
        #pragma unroll
        for (int j = 0; j < 2; j++) acc[i][j] = (floatx4){0.f, 0.f, 0.f, 0.f};

    for (int k0 = 0; k0 < HID; k0 += 64) {
        uint4 a0 = *(const uint4*)(ap + k0);
        uint4 a1 = *(const uint4*)(ap + k0 + 8);
        uint4 b0 = *(const uint4*)(bp + k0);
        uint4 b1 = *(const uint4*)(bp + k0 + 8);
        __syncthreads();
        *(uint4*)asw = a0; *(uint4*)(asw + 8) = a1;
        *(uint4*)bsw = b0; *(uint4*)(bsw + 8) = b1;
        __syncthreads();
        #pragma unroll
        for (int kk = 0; kk < 2; kk++) {
            bf16x8 af[2], bf[2];
            #pragma unroll
            for (int mi = 0; mi < 2; mi++)
                af[mi] = *(const bf16x8*)(As + (m0 + mi * 16 + l15) * 72 + kk * 32 + quad * 8);
            #pragma unroll
            for (int ni = 0; ni < 2; ni++)
                bf[ni] = *(const bf16x8*)(Bs + (n0 + ni * 16 + l15) * 72 + kk * 32 + quad * 8);
            #pragma unroll
            for (int mi = 0; mi < 2; mi++)
                #pragma unroll
                for (int ni = 0; ni < 2; ni++)
                    acc[mi][ni] = __builtin_amdgcn_mfma_f32_16x16x32_bf16(af[mi], bf[ni], acc[mi][ni], 0, 0, 0);
        }
    }
    const bool direct = (P == nullptr);
    #pragma unroll
    for (int mi = 0; mi < 2; mi++) {
        #pragma unroll
        for (int r = 0; r < 4; r++) {
            int mloc = m0 + mi * 16 + quad * 4 + r;
            int gi = mt * 64 + mloc;
            if (gi < cnt) {
                int slot = off + gi;
                #pragma unroll
                for (int ni = 0; ni < 2; ni++) {
                    int col = nt * 64 + n0 + ni * 16 + l15;
                    float v = acc[mi][ni][r];
                    if (direct) {
                        int tokr = rows[slot];
                        atomicAdd(&y[(size_t)tokr * DM + col], gates[slot] * v);
                    } else {
                        P[(size_t)slot * DM + col] = v;
                    }
                }
            }
        }
    }
}

// ---------------- combine: y[t] = g0*P[s0] + g1*P[s1] ----------------
__global__ void combine_kernel(const float* __restrict__ P, const int* __restrict__ slot_of,
                               const float* __restrict__ top_p, float* __restrict__ y) {
    int i = blockIdx.x * blockDim.x + threadIdx.x;    // per float4
    int t = i / (DM / 4);
    int c4 = i % (DM / 4);
    int s0 = slot_of[t * 2], s1 = slot_of[t * 2 + 1];
    float g0 = top_p[t * 2], g1 = top_p[t * 2 + 1];
    float4 a = ((const float4*)P)[(size_t)s0 * (DM / 4) + c4];
    float4 b = ((const float4*)P)[(size_t)s1 * (DM / 4) + c4];
    float4 o;
    o.x = g0 * a.x + g1 * b.x;
    o.y = g0 * a.y + g1 * b.y;
    o.z = g0 * a.z + g1 * b.z;
    o.w = g0 * a.w + g1 * b.w;
    ((float4*)y)[i] = o;
}

extern "C" void kernel_launch(void* const* d_in, const int* in_sizes, int n_in,
                              void* d_out, int out_size, void* d_ws, size_t ws_size,
                              hipStream_t stream) {
    (void)in_sizes; (void)n_in; (void)out_size;
    const float* x  = (const float*)d_in[0];
    const float* Wg = (const float*)d_in[1];
    const float* bg = (const float*)d_in[2];
    const float* W1 = (const float*)d_in[3];
    const float* W3 = (const float*)d_in[4];
    const float* W2 = (const float*)d_in[5];
    float* y = (float*)d_out;

    char* p = (char*)d_ws;
    auto carve = [&](size_t bytes) -> char* {
        char* r = p;
        p += (bytes + 255) & ~(size_t)255;
        return r;
    };
    unsigned short* xb   = (unsigned short*)carve((size_t)TOKENS * DM * 2);
    unsigned short* w1t  = (unsigned short*)carve((size_t)NE * DM * HID * 2);
    unsigned short* w3t  = (unsigned short*)carve((size_t)NE * DM * HID * 2);
    unsigned short* w2t  = (unsigned short*)carve((size_t)NE * HID * DM * 2);
    unsigned short* Hb   = (unsigned short*)carve((size_t)NSLOT * HID * 2);
    int*   rows    = (int*)carve(NSLOT * 4);
    float* gates   = (float*)carve(NSLOT * 4);
    int*   slot_of = (int*)carve(NSLOT * 4);
    int*   tidx    = (int*)carve((size_t)TOKENS * 2 * 4);
    float* tp      = (float*)carve((size_t)TOKENS * 2 * 4);
    int*   counts  = (int*)carve(256);
    int*   offsets = (int*)carve(256);
    int*   bhist   = (int*)carve((size_t)NB * NE * 4);
    int*   bases   = (int*)carve((size_t)NB * NE * 4);
    size_t base_need = (size_t)(p - (char*)d_ws);
    const size_t PBYTES = (size_t)NSLOT * DM * 4;
    float* P = nullptr;
    if (ws_size >= base_need + PBYTES) P = (float*)carve(PBYTES);

    init_kernel<<<dim3(1024), dim3(256), 0, stream>>>(y);
    cvt_x_kernel<<<dim3((TOKENS * DM / 8) / 256), dim3(256), 0, stream>>>(x, xb);
    cvt_transpose_kernel<<<dim3(NE * (DM / 32) * (HID / 32)), dim3(256), 0, stream>>>(W1, w1t, DM, HID);
    cvt_transpose_kernel<<<dim3(NE * (DM / 32) * (HID / 32)), dim3(256), 0, stream>>>(W3, w3t, DM, HID);
    cvt_transpose_kernel<<<dim3(NE * (HID / 32) * (DM / 32)), dim3(256), 0, stream>>>(W2, w2t, HID, DM);
    router_kernel<<<dim3(TOKENS / 4), dim3(256), 0, stream>>>(x, Wg, bg, tidx, tp);
    hist_kernel<<<dim3(NB), dim3(256), 0, stream>>>(tidx, bhist);
    prefix_kernel<<<dim3(1), dim3(64), 0, stream>>>(bhist, counts, offsets, bases);
    build_kernel<<<dim3(NB), dim3(256), 0, stream>>>(tidx, tp, bases, rows, gates, slot_of);
    gemm1_kernel<<<dim3(HID / 64, 128, NE), dim3(256), 0, stream>>>(xb, w1t, w3t, Hb, rows, counts, offsets);
    gemm2_kernel<<<dim3(DM / 64, 128, NE), dim3(256), 0, stream>>>(Hb, w2t, P, y, rows, gates, counts, offsets);
    if (P != nullptr)
        combine_kernel<<<dim3((TOKENS * DM / 4) / 256), dim3(256), 0, stream>>>(P, slot_of, tp, y);
}